// Round 10
// baseline (268.951 us; speedup 1.0000x reference)
//
#include <hip/hip_runtime.h>
#include <hip/hip_bf16.h>
#include <math.h>

#define VOLF 100.0f
#define FD 32
#define OUT_DIM 10
#define MAXN 320
#define MAX_LAUNCH_ITERS 4
#define SRW 2      // k_scan rows per wave
#define SRB 8      // k_scan rows per block (4 waves)
#define OB 128     // k_out partial blocks
#define CHUNK 28   // k_act0: k's per LDS chunk
#define NCHUNK 7   // 196/28 chunks per block
#define LDP 68     // padded wtT row stride (floats): 16B-aligned, bank-spread
#define PS 8       // partial slots (4 blockIdx.y * 2 wave-pairs)

// ---------------- K1: merged x-transpose (blocks < nxt) + per-neuron preprocess ----------------
__global__ __launch_bounds__(256) void k_prext(
    const float* __restrict__ x, const float* __restrict__ positions,
    const float* __restrict__ radii_in, const float* __restrict__ features,
    float* __restrict__ xT, float* __restrict__ posx4,
    float* __restrict__ radii, float* __restrict__ e_iw, float* __restrict__ e_ow,
    float* __restrict__ fn, float* __restrict__ scal, int N, int B, int IN, int nxt)
{
    if ((int)blockIdx.x < nxt) {           // transpose part: x[b][k] -> xT[k][b]
        int idx = blockIdx.x * 256 + threadIdx.x;
        if (idx < B * IN) {
            int b = idx / IN, k = idx % IN;
            xT[(size_t)k * B + b] = x[idx];
        }
        return;
    }
    int i = (blockIdx.x - nxt) * 256 + threadIdx.x;
    float my_iw = 0.0f, my_ow = 0.0f, my_r = 0.0f;
    if (i < N) {
        float px = fminf(fmaxf(positions[3*i+0], 0.1f), VOLF - 0.1f);
        float py = fminf(fmaxf(positions[3*i+1], 0.1f), VOLF - 0.1f);
        float pz = fminf(fmaxf(positions[3*i+2], 0.1f), VOLF - 0.1f);
        float sq = px*px + py*py + pz*pz;
        posx4[4*i+0] = px; posx4[4*i+1] = py; posx4[4*i+2] = pz; posx4[4*i+3] = sq;
        float r = fminf(fmaxf(radii_in[i], 1.0f), 50.0f);
        radii[i] = r; my_r = r;
        float xc = fminf(fmaxf(px / VOLF, 0.0f), 1.0f);
        my_iw = expf(-3.0f * xc);
        my_ow = expf(3.0f * (xc - 1.0f));
        e_iw[i] = my_iw; e_ow[i] = my_ow;
        float s = 0.0f;
        #pragma unroll
        for (int k = 0; k < FD; k++) { float v = features[(size_t)i*FD + k]; s += v*v; }
        float nrm = fmaxf(sqrtf(s), 1e-6f);
        #pragma unroll
        for (int k = 0; k < FD; k++) fn[(size_t)i*FD + k] = features[(size_t)i*FD + k] / nrm;
    }
    __shared__ float red[256];
    red[threadIdx.x] = my_iw; __syncthreads();
    for (int s = 128; s > 0; s >>= 1) { if (threadIdx.x < s) red[threadIdx.x] += red[threadIdx.x + s]; __syncthreads(); }
    if (threadIdx.x == 0) atomicAdd(&scal[0], red[0]);
    __syncthreads();
    red[threadIdx.x] = my_ow; __syncthreads();
    for (int s = 128; s > 0; s >>= 1) { if (threadIdx.x < s) red[threadIdx.x] += red[threadIdx.x + s]; __syncthreads(); }
    if (threadIdx.x == 0) atomicAdd(&scal[1], red[0]);
    if (i < N) atomicMax((int*)&scal[2], __float_as_int(my_r));
}

// ---------------- K3: outer-product partial GEMM: partial[slot][N][64] ----------------
// Block tile: 64 n x 64 b, K-quarter per blockIdx.y. Wave = full tile, k-interleaved.
// Per k: 1 per-lane ds_read_b128 (4 neurons) + 4 global b128 (16 batches) + 64 FMA.
__global__ __launch_bounds__(256) void k_act0(
    const float* __restrict__ xT, const float* __restrict__ Wi,
    float* __restrict__ partial, int N, int IN)
{
    __shared__ float smem[2 * 64 * 68];    // wtT chunk (28*68=1904) / epilogue buf (2*4096 as float4-laid)
    float* wtT = smem;
    int t = threadIdx.x;
    int wave = t >> 6, lane = t & 63;
    int nr = lane >> 2, br = lane & 3;     // A: 4n at nr*4 ; B: 16b at br*16
    int i0 = blockIdx.x * 64;
    int kbase = blockIdx.y * 196;
    float acc[4][16];
    #pragma unroll
    for (int a = 0; a < 4; a++)
        #pragma unroll
        for (int b = 0; b < 16; b++) acc[a][b] = 0.0f;

    for (int c = 0; c < NCHUNK; c++) {
        int k0 = kbase + c * CHUNK;
        __syncthreads();                   // guard previous chunk's reads
        for (int fi = t; fi < 64 * (CHUNK/4); fi += 256) {   // 448: transpose-stage W
            int n = fi / (CHUNK/4), q = fi % (CHUNK/4);
            float4 w4 = *(const float4*)(Wi + (size_t)(i0 + n) * IN + k0 + q * 4);
            wtT[(q*4+0)*LDP + n] = w4.x;
            wtT[(q*4+1)*LDP + n] = w4.y;
            wtT[(q*4+2)*LDP + n] = w4.z;
            wtT[(q*4+3)*LDP + n] = w4.w;
        }
        __syncthreads();
        for (int q = ((wave + c) & 3); q < CHUNK/4; q += 4) {
            #pragma unroll
            for (int j = 0; j < 4; j++) {
                int kl = q*4 + j;
                float4 a4 = *(const float4*)(&wtT[kl * LDP + nr*4]);
                const float* xr = xT + (size_t)(k0 + kl) * 64 + br*16;
                float4 b0 = *(const float4*)(xr + 0);
                float4 b1 = *(const float4*)(xr + 4);
                float4 b2 = *(const float4*)(xr + 8);
                float4 b3 = *(const float4*)(xr + 12);
                #pragma unroll
                for (int a = 0; a < 4; a++) {
                    float av = (a==0) ? a4.x : (a==1) ? a4.y : (a==2) ? a4.z : a4.w;
                    acc[a][ 0] += av*b0.x; acc[a][ 1] += av*b0.y; acc[a][ 2] += av*b0.z; acc[a][ 3] += av*b0.w;
                    acc[a][ 4] += av*b1.x; acc[a][ 5] += av*b1.y; acc[a][ 6] += av*b1.z; acc[a][ 7] += av*b1.w;
                    acc[a][ 8] += av*b2.x; acc[a][ 9] += av*b2.y; acc[a][10] += av*b2.z; acc[a][11] += av*b2.w;
                    acc[a][12] += av*b3.x; acc[a][13] += av*b3.y; acc[a][14] += av*b3.z; acc[a][15] += av*b3.w;
                }
            }
        }
    }
    // pairwise wave reduce: odd wave -> LDS, even wave adds + stores slot
    __syncthreads();
    float4* sm4 = (float4*)smem;
    int g = wave >> 1;
    if (wave & 1) {
        #pragma unroll
        for (int a = 0; a < 4; a++)
            #pragma unroll
            for (int b4 = 0; b4 < 4; b4++)
                sm4[(g*16 + a*4 + b4) * 64 + lane] =
                    make_float4(acc[a][b4*4+0], acc[a][b4*4+1], acc[a][b4*4+2], acc[a][b4*4+3]);
    }
    __syncthreads();
    if (!(wave & 1)) {
        int slot = blockIdx.y * 2 + g;
        size_t pbase = ((size_t)slot * N + i0 + nr*4) * 64 + br*16;
        #pragma unroll
        for (int a = 0; a < 4; a++)
            #pragma unroll
            for (int b4 = 0; b4 < 4; b4++) {
                float4 o = sm4[(g*16 + a*4 + b4) * 64 + lane];
                o.x += acc[a][b4*4+0]; o.y += acc[a][b4*4+1];
                o.z += acc[a][b4*4+2]; o.w += acc[a][b4*4+3];
                *(float4*)(partial + pbase + (size_t)a * 64 + b4*4) = o;
            }
    }
}

// ---------------- K3b: reduce 8 partials, apply input gating ----------------
__global__ __launch_bounds__(256) void k_act0_red(
    const float* __restrict__ partial, const float* __restrict__ e_iw,
    const float* __restrict__ scal, float* __restrict__ actA, int N)
{
    int idx = blockIdx.x * 256 + threadIdx.x;   // over N*64
    int i = idx >> 6;
    size_t stride = (size_t)N * 64;
    float s = 0.0f;
    #pragma unroll
    for (int p = 0; p < PS; p++) s += partial[p * stride + idx];
    float inv = 1.0f / (scal[0] + 1e-6f);
    actA[idx] = s * (e_iw[i] * inv);
}

// ---------------- K4 helper: one (row, j-batch) scan body ----------------
// EXACT reference predicate: dist = sqrtf(max(d2,0)); hit = dist < maxr.
__device__ __forceinline__ void scan_body(
    const float4& p, const float4& q, int j, float maxr,
    unsigned long long lmask, int2* __restrict__ ep, size_t base, int& cnt)
{
    float d2 = fmaxf(p.w + q.w - 2.0f*(p.x*q.x + p.y*q.y + p.z*q.z), 0.0f);
    float dist = sqrtf(d2);
    bool hit = dist < maxr;
    unsigned long long m = __ballot(hit);
    if (m) {
        if (hit) {
            int pos = cnt + (int)__popcll(m & lmask);
            if (pos < MAXN) ep[base + pos] = make_int2(j, __float_as_int(dist));
        }
        cnt += (int)__popcll(m);   // wave-uniform
    }
}

// ---------------- K4: dense scan + fused weight/rowsum (rows wave-private) ----------------
// N multiple of 64 but NOT 128: 128-wide main loop + 64-wide tail.
__global__ __launch_bounds__(256) void k_scan(
    const float* __restrict__ posx4, const float* __restrict__ scal,
    const float* __restrict__ fn, const float* __restrict__ radii,
    int2* __restrict__ ep, int* __restrict__ nbr_cnt, float* __restrict__ rowinv, int N)
{
    int wave = threadIdx.x >> 6, lane = threadIdx.x & 63;
    int r0 = blockIdx.x * SRB + wave * SRW;
    float4 p0 = ((const float4*)posx4)[r0];
    float4 p1 = ((const float4*)posx4)[r0 + 1];
    float maxr = __int_as_float(((const int*)scal)[2]);
    unsigned long long lmask = (1ull << lane) - 1ull;
    int c0 = 0, c1 = 0;
    size_t base0 = (size_t)r0 * MAXN, base1 = base0 + MAXN;
    int jb = 0;
    for (; jb + 128 <= N; jb += 128) {
        int j0 = jb + lane, j1 = jb + 64 + lane;
        float4 q0 = ((const float4*)posx4)[j0];
        float4 q1 = ((const float4*)posx4)[j1];
        scan_body(p0, q0, j0, maxr, lmask, ep, base0, c0);
        scan_body(p1, q0, j0, maxr, lmask, ep, base1, c1);
        scan_body(p0, q1, j1, maxr, lmask, ep, base0, c0);
        scan_body(p1, q1, j1, maxr, lmask, ep, base1, c1);
    }
    for (; jb < N; jb += 64) {
        int j0 = jb + lane;
        float4 q0 = ((const float4*)posx4)[j0];
        scan_body(p0, q0, j0, maxr, lmask, ep, base0, c0);
        scan_body(p1, q0, j0, maxr, lmask, ep, base1, c1);
    }
    if (lane == 0) {
        nbr_cnt[r0]     = min(c0, MAXN);
        nbr_cnt[r0 + 1] = min(c1, MAXN);
    }
    // fused weight pass: this wave owns rows r0, r0+1 (edges L1/L2-hot)
    int sub = lane & 7;        // float4 slot within fn row
    int eg  = lane >> 3;       // 8 edges per pass
    #pragma unroll
    for (int rr = 0; rr < SRW; rr++) {
        int r = r0 + rr;
        int cnt = min(rr == 0 ? c0 : c1, MAXN);
        size_t base = (size_t)r * MAXN;
        float4 fni = ((const float4*)(fn + (size_t)r * FD))[sub];
        float inv_ri = 1.0f / (radii[r] + 1e-6f);
        float s = 0.0f;
        for (int e0 = 0; e0 < cnt; e0 += 8) {
            int e = e0 + eg;
            bool act = e < cnt;
            int ecl = act ? e : cnt - 1;
            int2 edge = ep[base + ecl];
            float dist = __int_as_float(edge.y);
            float4 fj = ((const float4*)(fn + (size_t)edge.x * FD))[sub];
            float fs = fni.x*fj.x + fni.y*fj.y + fni.z*fj.z + fni.w*fj.w;
            fs += __shfl_xor(fs, 1, 64);
            fs += __shfl_xor(fs, 2, 64);
            fs += __shfl_xor(fs, 4, 64);
            fs = fminf(fmaxf(fs, -1.0f), 1.0f);
            float w = expf(-fminf(dist * inv_ri, 20.0f)) * (0.3f + 0.7f * fs);
            if (act && sub == 0) {
                ((float*)&ep[base + e])[1] = w;
                s += w;
            }
        }
        // full-wave butterfly (non-writer lanes hold 0)
        s += __shfl_xor(s, 1, 64);  s += __shfl_xor(s, 2, 64);  s += __shfl_xor(s, 4, 64);
        s += __shfl_xor(s, 8, 64);  s += __shfl_xor(s, 16, 64); s += __shfl_xor(s, 32, 64);
        if (lane == 0) rowinv[r] = 1.0f / (s + 1e-6f);
    }
}

// ---------------- K5: one iteration (sparse matvec over 64 batches) ----------------
__global__ __launch_bounds__(256) void k_iter(
    const float* __restrict__ actIn, float* __restrict__ actOut,
    const int2* __restrict__ ep, const int* __restrict__ nbr_cnt,
    const float* __restrict__ rowinv, const float* __restrict__ thr,
    const int* __restrict__ nIterPtr, int iterIdx, int N)
{
    if (iterIdx >= min(*nIterPtr, MAX_LAUNCH_ITERS)) return;   // inactive launch: no-op
    int i = blockIdx.x;
    int wave = threadIdx.x >> 6, lane = threadIdx.x & 63;
    int cnt = nbr_cnt[i];
    float acc = 0.0f;
    for (int e = wave; e < cnt; e += 4) {
        int2 edge = ep[(size_t)i * MAXN + e];
        acc += actIn[(size_t)edge.x * 64 + lane] * __int_as_float(edge.y);
    }
    __shared__ float redA[4 * 64];
    redA[wave * 64 + lane] = acc;
    __syncthreads();
    if (wave == 0) {
        float tot = redA[lane] + redA[64 + lane] + redA[128 + lane] + redA[192 + lane];
        float v = actIn[(size_t)i * 64 + lane] + tot * rowinv[i] - thr[i];
        v = fminf(fmaxf(v, 0.0f), 100.0f);
        actOut[(size_t)i * 64 + lane] = v;
    }
}

// ---------------- K6a: output projection partials ----------------
__global__ __launch_bounds__(256) void k_out1(
    const float* __restrict__ actA, const float* __restrict__ actB,
    const int* __restrict__ nIterPtr, const float* __restrict__ e_ow,
    const float* __restrict__ scal, const float* __restrict__ outW,
    float* __restrict__ outPart, int N)
{
    int m = min(*nIterPtr, MAX_LAUNCH_ITERS);
    const float* actF = (m & 1) ? actB : actA;
    int wave = threadIdx.x >> 6, lane = threadIdx.x & 63;
    float inv = 1.0f / (scal[1] + 1e-6f);
    float acc[OUT_DIM];
    #pragma unroll
    for (int o = 0; o < OUT_DIM; o++) acc[o] = 0.0f;
    for (int i = blockIdx.x * 4 + wave; i < N; i += OB * 4) {
        float a = actF[(size_t)i * 64 + lane] * (e_ow[i] * inv);
        const float* wo = outW + (size_t)i * OUT_DIM;
        #pragma unroll
        for (int o = 0; o < OUT_DIM; o++) acc[o] += a * wo[o];
    }
    __shared__ float red[4][OUT_DIM][64];
    #pragma unroll
    for (int o = 0; o < OUT_DIM; o++) red[wave][o][lane] = acc[o];
    __syncthreads();
    if (wave == 0) {
        #pragma unroll
        for (int o = 0; o < OUT_DIM; o++) {
            float s = red[0][o][lane] + red[1][o][lane] + red[2][o][lane] + red[3][o][lane];
            outPart[((size_t)blockIdx.x * OUT_DIM + o) * 64 + lane] = s;
        }
    }
}

// ---------------- K6b: reduce partials -> out[b*10+o] ----------------
__global__ __launch_bounds__(256) void k_out2(
    const float* __restrict__ outPart, float* __restrict__ out)
{
    int t = blockIdx.x * 256 + threadIdx.x;     // over 640
    if (t >= 64 * OUT_DIM) return;
    int b = t / OUT_DIM, o = t % OUT_DIM;
    float s = 0.0f;
    for (int blk = 0; blk < OB; blk++)
        s += outPart[((size_t)blk * OUT_DIM + o) * 64 + b];
    out[t] = s;
}

extern "C" void kernel_launch(void* const* d_in, const int* in_sizes, int n_in,
                              void* d_out, int out_size, void* d_ws, size_t ws_size,
                              hipStream_t stream)
{
    const float* x        = (const float*)d_in[0];
    const float* positions= (const float*)d_in[1];
    const float* Win      = (const float*)d_in[2];
    const float* features = (const float*)d_in[3];
    const float* Wout     = (const float*)d_in[4];
    const float* radii_in = (const float*)d_in[5];
    const float* thr      = (const float*)d_in[6];
    const int*   nIter    = (const int*)  d_in[7];

    const int N  = in_sizes[5];            // 8000
    const int IN = in_sizes[2] / N;        // 784
    const int B  = in_sizes[0] / IN;       // 64 (kernels assume 64 = wave size)

    float* ws = (float*)d_ws;
    size_t off = 0;
    auto alloc = [&](size_t nfloats) { size_t cur = off; off += (nfloats + 63) & ~(size_t)63; return cur; };
    float* xT      = ws + alloc((size_t)B * IN);
    float* posx4   = ws + alloc((size_t)N * 4);
    float* radii   = ws + alloc(N);
    float* e_iw    = ws + alloc(N);
    float* e_ow    = ws + alloc(N);
    float* rowinv  = ws + alloc(N);
    float* scal    = ws + alloc(4);
    float* outPart = ws + alloc((size_t)OB * OUT_DIM * 64);
    float* fn      = ws + alloc((size_t)N * FD);
    float* actA    = ws + alloc((size_t)N * 64);
    float* actB    = ws + alloc((size_t)N * 64);
    int2*  ep      = (int2*)(ws + alloc((size_t)N * MAXN * 2));   // packed (j, dist/w)
    int*   nbr_cnt = (int*)(ws + alloc(N));
    // partial[PS][N][64] aliased onto ep (consumed by k_act0_red before k_scan writes ep)
    float* partial = (float*)ep;   // PS*N*64 = 4.096M floats <= N*MAXN*2 = 5.12M floats

    hipMemsetAsync(scal, 0, 4 * sizeof(float), stream);

    int nxt = (B * IN + 255) / 256;        // 196 transpose blocks
    int npre = (N + 255) / 256;            // 32 preprocess blocks
    k_prext<<<nxt + npre, 256, 0, stream>>>(x, positions, radii_in, features,
                                            xT, posx4, radii, e_iw, e_ow, fn, scal,
                                            N, B, IN, nxt);
    k_act0<<<dim3(N / 64, 4), 256, 0, stream>>>(xT, Win, partial, N, IN);
    k_act0_red<<<(N * 64) / 256, 256, 0, stream>>>(partial, e_iw, scal, actA, N);
    k_scan<<<N / SRB, 256, 0, stream>>>(posx4, scal, fn, radii, ep, nbr_cnt, rowinv, N);

    float* bufs[2] = {actA, actB};
    for (int it = 0; it < MAX_LAUNCH_ITERS; it++) {
        k_iter<<<N, 256, 0, stream>>>(bufs[it & 1], bufs[(it + 1) & 1],
                                      ep, nbr_cnt, rowinv, thr, nIter, it, N);
    }
    k_out1<<<OB, 256, 0, stream>>>(actA, actB, nIter, e_ow, scal, Wout, outPart, N);
    k_out2<<<3, 256, 0, stream>>>(outPart, (float*)d_out);
}